// Round 1
// baseline (309.195 us; speedup 1.0000x reference)
//
#include <hip/hip_runtime.h>

typedef __attribute__((ext_vector_type(8))) short bf16x8;
typedef __attribute__((ext_vector_type(4))) float f32x4;

#define TM 16          // tokens per block
#define CH 256         // channels
#define CPAD 264       // padded LDS row (bank-conflict avoidance, keeps 16B align)

__device__ __forceinline__ unsigned short f2bf(float f) {
    unsigned u = __builtin_bit_cast(unsigned, f);
    u += 0x7FFFu + ((u >> 16) & 1u);        // RNE
    return (unsigned short)(u >> 16);
}

// B-fragment: 8 consecutive c of weight row o, fp32 -> bf16
__device__ __forceinline__ bf16x8 bfragW(const float* __restrict__ W, int o, int c0) {
    const float4* p = (const float4*)(W + o * CH + c0);
    float4 x = p[0], y = p[1];
    bf16x8 r;
    r[0] = (short)f2bf(x.x); r[1] = (short)f2bf(x.y);
    r[2] = (short)f2bf(x.z); r[3] = (short)f2bf(x.w);
    r[4] = (short)f2bf(y.x); r[5] = (short)f2bf(y.y);
    r[6] = (short)f2bf(y.z); r[7] = (short)f2bf(y.w);
    return r;
}

__global__ __launch_bounds__(512, 2)
void avd_fused_kernel(const float* __restrict__ xa, const float* __restrict__ xv,
                      const float* __restrict__ xd,
                      const float* __restrict__ Wtt, const float* __restrict__ Wtr,
                      const float* __restrict__ Wtd, const float* __restrict__ Wvd,
                      const float* __restrict__ Wdv,
                      float* __restrict__ out)
{
    // feature slots 0..8: x_d (untransposed, c-order q=i*3+j); 9: x_a; 10..12: x_v comps
    __shared__ __attribute__((aligned(16))) unsigned short feat[13][TM][CPAD];
    // aux slots: 0: trace(D1); 1..3: axial(D1)
    __shared__ __attribute__((aligned(16))) unsigned short aux4[4][TM][CPAD];

    const int tid  = threadIdx.x;
    const int lane = tid & 63;
    const int wid  = tid >> 6;          // 0..7
    const int m0   = blockIdx.x * TM;

    float* out_xa = out;                 // 16384*256
    float* out_xv = out + 4194304;       // 16384*256*3
    float* out_xd = out + 16777216;      // 16384*256*9

    // ---------------- stage features (fp32 -> bf16 LDS) ----------------
    {   // x_d: 16*2304 floats = 9216 float4, 18 per thread, fully coalesced
        const float4* src = (const float4*)(xd + (size_t)m0 * 2304);
        #pragma unroll
        for (int it = 0; it < 18; ++it) {
            int i4 = tid + it * 512;
            float4 v = src[i4];
            float ve[4] = {v.x, v.y, v.z, v.w};
            int g = i4 * 4;
            #pragma unroll
            for (int e = 0; e < 4; ++e) {
                int gg  = g + e;
                int m   = gg / 2304;
                int rem = gg - m * 2304;
                int c   = rem / 9;
                int p   = rem - c * 9;
                feat[p][m][c] = f2bf(ve[e]);
            }
        }
    }
    {   // x_a: 4096 floats = 1024 float4
        const float4* src = (const float4*)(xa + (size_t)m0 * 256);
        #pragma unroll
        for (int it = 0; it < 2; ++it) {
            int i4 = tid + it * 512;
            float4 v = src[i4];
            int g = i4 * 4;
            int m = g >> 8;
            int c = g & 255;
            feat[9][m][c + 0] = f2bf(v.x);
            feat[9][m][c + 1] = f2bf(v.y);
            feat[9][m][c + 2] = f2bf(v.z);
            feat[9][m][c + 3] = f2bf(v.w);
        }
    }
    {   // x_v: 12288 floats = 3072 float4
        const float4* src = (const float4*)(xv + (size_t)m0 * 768);
        #pragma unroll
        for (int it = 0; it < 6; ++it) {
            int i4 = tid + it * 512;
            float4 v = src[i4];
            float ve[4] = {v.x, v.y, v.z, v.w};
            int g = i4 * 4;
            #pragma unroll
            for (int e = 0; e < 4; ++e) {
                int gg  = g + e;
                int m   = gg / 768;
                int rem = gg - m * 768;
                int c   = rem / 3;
                int i   = rem - c * 3;
                feat[10 + i][m][c] = f2bf(ve[e]);
            }
        }
    }
    __syncthreads();

    const int am = lane & 15;   // A-frag row (token within tile)
    const int aq = lane >> 4;   // A/B-frag k-quarter

    // ---------------- phase 1: TensTrans(9) + TensDelta(1) + w=Wvd*xv(3) ----------------
    #pragma unroll 1
    for (int np = 0; np < 2; ++np) {
        const int nt    = np * 8 + wid;        // 0..15
        const int obase = nt * 16;
        const int o     = obase + (lane & 15); // B-frag / output column
        f32x4 acc[13];
        #pragma unroll
        for (int p = 0; p < 13; ++p) acc[p] = (f32x4){0.f, 0.f, 0.f, 0.f};

        for (int ks = 0; ks < 8; ++ks) {
            const int c0 = ks * 32 + aq * 8;
            bf16x8 a[13];
            #pragma unroll
            for (int p = 0; p < 13; ++p)
                a[p] = *(const bf16x8*)&feat[p][am][c0];
            bf16x8 btt = bfragW(Wtt, o, c0);
            bf16x8 btd = bfragW(Wtd, o, c0);
            bf16x8 bvd = bfragW(Wvd, o, c0);
            #pragma unroll
            for (int q = 0; q < 9; ++q)
                acc[q] = __builtin_amdgcn_mfma_f32_16x16x32_bf16(a[q], btt, acc[q], 0, 0, 0);
            acc[9] = __builtin_amdgcn_mfma_f32_16x16x32_bf16(a[9], btd, acc[9], 0, 0, 0);
            #pragma unroll
            for (int i = 0; i < 3; ++i)
                acc[10 + i] = __builtin_amdgcn_mfma_f32_16x16x32_bf16(a[10 + i], bvd, acc[10 + i], 0, 0, 0);
        }

        // epilogue: lane holds (m = (lane>>4)*4 + r, o) for r=0..3
        #pragma unroll
        for (int r = 0; r < 4; ++r) {
            const int m = (lane >> 4) * 4 + r;
            const size_t row = (size_t)(m0 + m) * 256 + o;
            const float* d0 = xd + row * 9;
            float d[9], t[9];
            #pragma unroll
            for (int q = 0; q < 9; ++q) { d[q] = d0[q]; t[q] = acc[q][r]; }
            const float delta = acc[9][r];
            const float w0 = acc[10][r], w1 = acc[11][r], w2 = acc[12][r];
            // D1[i][j] = d[i*3+j] + t[j*3+i];  out = D1 + delta*I + cross(w)
            float* po = out_xd + row * 9;
            po[0] = d[0] + t[0] + delta;
            po[1] = d[1] + t[3] - w2;
            po[2] = d[2] + t[6] + w1;
            po[3] = d[3] + t[1] + w2;
            po[4] = d[4] + t[4] + delta;
            po[5] = d[5] + t[7] - w0;
            po[6] = d[6] + t[2] - w1;
            po[7] = d[7] + t[5] + w0;
            po[8] = d[8] + t[8] + delta;
            // layer-2 inputs: trace(D1), axial(D1)
            aux4[0][m][o] = f2bf(d[0] + t[0] + d[4] + t[4] + d[8] + t[8]);
            aux4[1][m][o] = f2bf((d[5] + t[7]) - (d[7] + t[5]));
            aux4[2][m][o] = f2bf((d[6] + t[2]) - (d[2] + t[6]));
            aux4[3][m][o] = f2bf((d[1] + t[3]) - (d[3] + t[1]));
        }
    }
    __syncthreads();

    // ---------------- phase 2: TensTrace + ChiralMix dv ----------------
    {
        const int s = wid & 3;      // 0: x_a (trace), 1..3: x_v comp k=s-1
        const int h = wid >> 2;     // o-half
        const float* W2 = (s == 0) ? Wtr : Wdv;
        #pragma unroll 1
        for (int nt2 = 0; nt2 < 8; ++nt2) {
            const int obase = (h * 8 + nt2) * 16;
            const int o = obase + (lane & 15);
            f32x4 acc = (f32x4){0.f, 0.f, 0.f, 0.f};
            for (int ks = 0; ks < 8; ++ks) {
                const int c0 = ks * 32 + aq * 8;
                bf16x8 a = *(const bf16x8*)&aux4[s][am][c0];
                bf16x8 b = bfragW(W2, o, c0);
                acc = __builtin_amdgcn_mfma_f32_16x16x32_bf16(a, b, acc, 0, 0, 0);
            }
            #pragma unroll
            for (int r = 0; r < 4; ++r) {
                const int m = (lane >> 4) * 4 + r;
                const size_t row = (size_t)(m0 + m) * 256 + o;
                if (s == 0) {
                    out_xa[row] = xa[row] + acc[r];
                } else {
                    const size_t idx = row * 3 + (s - 1);
                    out_xv[idx] = xv[idx] + acc[r];
                }
            }
        }
    }
}

extern "C" void kernel_launch(void* const* d_in, const int* in_sizes, int n_in,
                              void* d_out, int out_size, void* d_ws, size_t ws_size,
                              hipStream_t stream) {
    const float* xa  = (const float*)d_in[0];
    const float* xv  = (const float*)d_in[1];
    const float* xd  = (const float*)d_in[2];
    const float* Wtt = (const float*)d_in[3];
    const float* Wtr = (const float*)d_in[4];
    const float* Wtd = (const float*)d_in[5];
    const float* Wvd = (const float*)d_in[6];
    const float* Wdv = (const float*)d_in[7];
    float* out = (float*)d_out;

    avd_fused_kernel<<<dim3(16384 / TM), dim3(512), 0, stream>>>(
        xa, xv, xd, Wtt, Wtr, Wtd, Wvd, Wdv, out);
}